// Round 5
// baseline (579.085 us; speedup 1.0000x reference)
//
#include <hip/hip_runtime.h>
#include <hip/hip_bf16.h>

#define N_NODES 8192
#define MAXD 128

typedef __attribute__((ext_vector_type(8))) __bf16 bf16x8;
typedef __attribute__((ext_vector_type(4))) float floatx4;

__device__ __forceinline__ void async16(void* lds, const void* g) {
  __builtin_amdgcn_global_load_lds((const __attribute__((address_space(1))) void*)g,
                                   (__attribute__((address_space(3))) void*)lds, 16, 0, 0);
}

__device__ __forceinline__ float bfu(unsigned short u) {
  union { unsigned int i; float f; } c; c.i = (unsigned int)u << 16; return c.f;
}

// ---------------- prep (transposes, hi/lo splits, x->bf16, stats zero) + CSR build ----------------
__global__ __launch_bounds__(256) void prep_csr(const float* __restrict__ mlp_W1,
                                                const float* __restrict__ mlp_W2,
                                                const float* __restrict__ att_W1,
                                                const float* __restrict__ pred_W,
                                                const float* __restrict__ mask_W1,
                                                const float* __restrict__ x,
                                                const float* __restrict__ graph,
                                                __hip_bfloat16* __restrict__ Wt1,
                                                __hip_bfloat16* __restrict__ Wt2,
                                                __hip_bfloat16* __restrict__ attHi,
                                                __hip_bfloat16* __restrict__ attLo,
                                                __hip_bfloat16* __restrict__ predWt,
                                                __hip_bfloat16* __restrict__ maskHi,
                                                __hip_bfloat16* __restrict__ maskLo,
                                                __hip_bfloat16* __restrict__ hbHi,
                                                __hip_bfloat16* __restrict__ hbLo,
                                                float* __restrict__ stats,
                                                int* __restrict__ col_idx,
                                                int* __restrict__ deg) {
  __shared__ union { float tile[32][33]; int cnt; } sm;
  const int blk = blockIdx.x, tid = threadIdx.x;
  if (blk >= 994) {  // CSR: block per row, 2048 loads in flight
    const int i = blk - 994;
    if (tid == 0) sm.cnt = 0;
    __syncthreads();
    const float4* row = (const float4*)(graph + (size_t)i * N_NODES);
#pragma unroll
    for (int it = 0; it < 8; ++it) {
      const int idx = it * 256 + tid;
      float4 v = row[idx];
      if (v.x > 0.f) { int p = atomicAdd(&sm.cnt, 1); if (p < MAXD) col_idx[(size_t)i * MAXD + p] = idx * 4 + 0; }
      if (v.y > 0.f) { int p = atomicAdd(&sm.cnt, 1); if (p < MAXD) col_idx[(size_t)i * MAXD + p] = idx * 4 + 1; }
      if (v.z > 0.f) { int p = atomicAdd(&sm.cnt, 1); if (p < MAXD) col_idx[(size_t)i * MAXD + p] = idx * 4 + 2; }
      if (v.w > 0.f) { int p = atomicAdd(&sm.cnt, 1); if (p < MAXD) col_idx[(size_t)i * MAXD + p] = idx * 4 + 3; }
    }
    __syncthreads();
    if (tid == 0) deg[i] = sm.cnt < MAXD ? sm.cnt : MAXD;
    return;
  }
  if (blk < 480) {
    const int tx = tid & 31, ty = tid >> 5;
    const float* in; __hip_bfloat16* oh; __hip_bfloat16* ol = nullptr;
    int K, N, kt, nt;
    if (blk < 384) {
      const int z = blk / 64, rem = blk % 64; kt = rem / 8; nt = rem % 8; K = 256; N = 256;
      in = z < 3 ? mlp_W1 + (size_t)z * 65536 : mlp_W2 + (size_t)(z - 3) * 65536;
      oh = z < 3 ? Wt1 + (size_t)z * 65536 : Wt2 + (size_t)(z - 3) * 65536;
    } else if (blk < 432) {
      const int i = blk - 384, z = i / 16, rem = i % 16; kt = rem / 2; nt = rem & 1;
      K = 256; N = 64;
      in = att_W1 + (size_t)z * 16384; oh = attHi + (size_t)z * 16384;
      ol = attLo + (size_t)z * 16384;
    } else {
      const int i = blk - 432; kt = i / 2; nt = i & 1; K = 768; N = 64;
      in = pred_W; oh = predWt;
    }
    const int k0 = kt * 32, n0 = nt * 32;
#pragma unroll
    for (int r = 0; r < 4; ++r)
      sm.tile[ty + r * 8][tx] = in[(size_t)(k0 + ty + r * 8) * N + n0 + tx];
    __syncthreads();
#pragma unroll
    for (int r = 0; r < 4; ++r) {
      const float v = sm.tile[tx][ty + r * 8];
      const __hip_bfloat16 hi = __float2bfloat16(v);
      oh[(size_t)(n0 + ty + r * 8) * K + k0 + tx] = hi;
      if (ol)
        ol[(size_t)(n0 + ty + r * 8) * K + k0 + tx] =
            __float2bfloat16(v - __bfloat162float(hi));
    }
  } else if (blk == 480) {
    for (int i = tid; i < 16384; i += 256) {
      const int n = i >> 8, k = i & 255;
      const float v = (n < 54) ? mask_W1[k * 54 + n] : 0.f;
      const __hip_bfloat16 hi = __float2bfloat16(v);
      maskHi[n * 256 + k] = hi;
      maskLo[n * 256 + k] = __float2bfloat16(v - __bfloat162float(hi));
    }
  } else if (blk == 481) {
    for (int i = tid; i < 1536; i += 256) stats[i] = 0.f;
  } else {
    const float4* xv = (const float4*)x;
    const int base = (blk - 482) * 1024;
#pragma unroll
    for (int it = 0; it < 4; ++it) {
      const int i = base + it * 256 + tid;
      const float4 v = xv[i];
      union { __hip_bfloat16 h[4]; short4 s4; } ph, pl;
      ph.h[0] = __float2bfloat16(v.x); ph.h[1] = __float2bfloat16(v.y);
      ph.h[2] = __float2bfloat16(v.z); ph.h[3] = __float2bfloat16(v.w);
      pl.h[0] = __float2bfloat16(v.x - __bfloat162float(ph.h[0]));
      pl.h[1] = __float2bfloat16(v.y - __bfloat162float(ph.h[1]));
      pl.h[2] = __float2bfloat16(v.z - __bfloat162float(ph.h[2]));
      pl.h[3] = __float2bfloat16(v.w - __bfloat162float(ph.h[3]));
      ((short4*)hbHi)[i] = ph.s4;
      ((short4*)hbLo)[i] = pl.s4;
    }
  }
}

// ---------------- 64x64 MFMA tile accumulate (for emlp0 only) ----------------
__device__ __forceinline__ void gemm_acc(char* AsB, char* WsB,
                                         const __hip_bfloat16* __restrict__ A,
                                         const __hip_bfloat16* __restrict__ Bt,
                                         int K, int m0, int n0, floatx4* acc) {
  const int tid = threadIdx.x, w = tid >> 6, lane = tid & 63;
  const int q = lane >> 4, l15 = lane & 15;
  const int nKT = K >> 6;
  for (int kt = 0; kt < nKT; ++kt) {
    const int kbase = kt * 64;
#pragma unroll
    for (int r = 0; r < 2; ++r) {
      const int s = w * 128 + r * 64 + lane;
      const int m = s >> 3;
      const int gch = (s & 7) ^ (m & 7);
      async16(AsB + (size_t)(w * 128 + r * 64) * 16,
              (const void*)(A + (size_t)(m0 + m) * K + kbase + gch * 8));
      async16(WsB + (size_t)(w * 128 + r * 64) * 16,
              (const void*)(Bt + (size_t)(n0 + m) * K + kbase + gch * 8));
    }
    __syncthreads();
#pragma unroll
    for (int kk = 0; kk < 2; ++kk) {
      const int gq = kk * 4 + q;
      const int nsl = w * 16 + l15;
      bf16x8 b = *(const bf16x8*)(WsB + (size_t)(nsl * 8 + (gq ^ (nsl & 7))) * 16);
#pragma unroll
      for (int mt = 0; mt < 4; ++mt) {
        const int msl = mt * 16 + l15;
        bf16x8 a = *(const bf16x8*)(AsB + (size_t)(msl * 8 + (gq ^ (msl & 7))) * 16);
        acc[mt] = __builtin_amdgcn_mfma_f32_16x16x32_bf16(a, b, acc[mt], 0, 0, 0);
      }
    }
    __syncthreads();
  }
}

// ---------------- layer-0 e/mask MLP via MFMA, hi/lo split ----------------
union EmlpSM {
  struct { char As[8192]; char Ws[8192]; } g;
  float red[64 * 65];
};

__global__ __launch_bounds__(256) void emlp_kernel(
    const __hip_bfloat16* __restrict__ hbHi, const __hip_bfloat16* __restrict__ hbLo,
    const __hip_bfloat16* __restrict__ aHi, const __hip_bfloat16* __restrict__ aLo,
    const float* __restrict__ ab1, const float* __restrict__ aw2, const float* __restrict__ ab2,
    const __hip_bfloat16* __restrict__ mHi, const __hip_bfloat16* __restrict__ mLo,
    const float* __restrict__ mb1, const float* __restrict__ mw2, const float* __restrict__ mb2,
    float* __restrict__ evec, float* __restrict__ maskL) {
  __shared__ EmlpSM sm;
  const int tid = threadIdx.x, w = tid >> 6, lane = tid & 63;
  const int q = lane >> 4, l15 = lane & 15;
  const bool is_mask = blockIdx.x >= 128;
  const int m0 = (is_mask ? (int)blockIdx.x - 128 : (int)blockIdx.x) * 64;
  const __hip_bfloat16* Whi = is_mask ? mHi : aHi;
  const __hip_bfloat16* Wlo = is_mask ? mLo : aLo;
  floatx4 acc[4] = {};
  gemm_acc(sm.g.As, sm.g.Ws, hbHi, Whi, 256, m0, 0, acc);
  gemm_acc(sm.g.As, sm.g.Ws, hbHi, Wlo, 256, m0, 0, acc);
  gemm_acc(sm.g.As, sm.g.Ws, hbLo, Whi, 256, m0, 0, acc);
  const int n = w * 16 + l15;
  float b1v, w2v, b2v;
  if (is_mask) {
    b1v = n < 54 ? mb1[n] : 0.f;
    w2v = n < 54 ? mw2[n] : 0.f;
    b2v = mb2[0];
  } else {
    b1v = ab1[n]; w2v = aw2[n]; b2v = ab2[0];
  }
#pragma unroll
  for (int mt = 0; mt < 4; ++mt)
#pragma unroll
    for (int r2 = 0; r2 < 4; ++r2)
      sm.red[n * 65 + mt * 16 + q * 4 + r2] = fmaxf(acc[mt][r2] + b1v, 0.f) * w2v;
  __syncthreads();
  if (tid < 64) {
    float s = 0.f;
#pragma unroll
    for (int nn = 0; nn < 64; ++nn) s += sm.red[nn * 65 + tid];
    const float z = s + b2v;
    if (!is_mask) {
      evec[m0 + tid] = z;
    } else {
      const float thr = 3.f / (1.f + expf(-z));
#pragma unroll
      for (int li = 0; li < 3; ++li) {
        const float dd = (float)li - thr;
        maskL[li * N_NODES + m0 + tid] = expf(-dd * dd);
      }
    }
  }
}

// ---------------- X: agg (16 rows) + GEMM1 + GEMM2 + stats, fully fused ----------------
__global__ __launch_bounds__(256) void layer_x(const __hip_bfloat16* __restrict__ hb,
                                               const float* __restrict__ evec,
                                               const int* __restrict__ col_idx,
                                               const int* __restrict__ deg,
                                               const __hip_bfloat16* __restrict__ W1,
                                               const float* __restrict__ b1,
                                               const __hip_bfloat16* __restrict__ W2,
                                               const float* __restrict__ b2,
                                               float* __restrict__ h2,
                                               float* __restrict__ stats) {
  __shared__ __hip_bfloat16 Astrip[16][264];
  __shared__ __hip_bfloat16 Hstrip[16][264];
  const int tid = threadIdx.x, w = tid >> 6, lane = tid & 63;
  const int q = lane >> 4, l15 = lane & 15;
  const int m0 = blockIdx.x * 16;

  // Phase A: sparse softmax aggregation, 4 nodes per wave, result -> Astrip (bf16)
#pragma unroll
  for (int t = 0; t < 4; ++t) {
    const int i = w * 4 + t;
    const int node = m0 + i;
    const int d = deg[node];
    int c0 = 0, c1 = 0;
    float e0 = -3.0e38f, e1 = -3.0e38f;
    if (lane < d) { c0 = col_idx[(size_t)node * MAXD + lane]; e0 = evec[c0]; }
    if (lane + 64 < d) { c1 = col_idx[(size_t)node * MAXD + lane + 64]; e1 = evec[c1]; }
    float mx = fmaxf(e0, e1);
#pragma unroll
    for (int off = 32; off; off >>= 1) mx = fmaxf(mx, __shfl_xor(mx, off));
    float p0 = lane < d ? expf(e0 - mx) : 0.f;
    float p1 = lane + 64 < d ? expf(e1 - mx) : 0.f;
    float s = p0 + p1;
#pragma unroll
    for (int off = 32; off; off >>= 1) s += __shfl_xor(s, off);
    const float scale = (float)d / s;
    p0 *= scale; p1 *= scale;
    float4 a = {0.f, 0.f, 0.f, 0.f};
    int j = 0;
    for (; j + 2 <= d; j += 2) {
      const int ca = __shfl(j < 64 ? c0 : c1, j & 63);
      const int cb = __shfl(j + 1 < 64 ? c0 : c1, (j + 1) & 63);
      const float wa = __shfl(j < 64 ? p0 : p1, j & 63);
      const float wb = __shfl(j + 1 < 64 ? p0 : p1, (j + 1) & 63);
      const ushort4 ua = *(const ushort4*)(hb + (size_t)ca * 256 + lane * 4);
      const ushort4 ub = *(const ushort4*)(hb + (size_t)cb * 256 + lane * 4);
      a.x += wa * bfu(ua.x) + wb * bfu(ub.x);
      a.y += wa * bfu(ua.y) + wb * bfu(ub.y);
      a.z += wa * bfu(ua.z) + wb * bfu(ub.z);
      a.w += wa * bfu(ua.w) + wb * bfu(ub.w);
    }
    if (j < d) {
      const int ca = __shfl(j < 64 ? c0 : c1, j & 63);
      const float wa = __shfl(j < 64 ? p0 : p1, j & 63);
      const ushort4 ua = *(const ushort4*)(hb + (size_t)ca * 256 + lane * 4);
      a.x += wa * bfu(ua.x); a.y += wa * bfu(ua.y);
      a.z += wa * bfu(ua.z); a.w += wa * bfu(ua.w);
    }
    union { __hip_bfloat16 h[4]; short4 s4; } pk;
    pk.h[0] = __float2bfloat16(a.x); pk.h[1] = __float2bfloat16(a.y);
    pk.h[2] = __float2bfloat16(a.z); pk.h[3] = __float2bfloat16(a.w);
    *(short4*)&Astrip[i][lane * 4] = pk.s4;
  }
  __syncthreads();

  // Phase B: GEMM1 (A from LDS strip, W fragments direct from L2) + bias + relu -> Hstrip
  {
    floatx4 acc1[4] = {};
    for (int kc = 0; kc < 8; ++kc) {
      const int kb = kc * 32 + q * 8;
      const bf16x8 a = *(const bf16x8*)&Astrip[l15][kb];
#pragma unroll
      for (int nt = 0; nt < 4; ++nt) {
        const bf16x8 b = *(const bf16x8*)(W1 + (size_t)(w * 64 + nt * 16 + l15) * 256 + kb);
        acc1[nt] = __builtin_amdgcn_mfma_f32_16x16x32_bf16(a, b, acc1[nt], 0, 0, 0);
      }
    }
#pragma unroll
    for (int nt = 0; nt < 4; ++nt) {
      const int n = w * 64 + nt * 16 + l15;
      const float bv = b1[n];
#pragma unroll
      for (int r2 = 0; r2 < 4; ++r2)
        Hstrip[q * 4 + r2][n] = __float2bfloat16(fmaxf(acc1[nt][r2] + bv, 0.f));
    }
  }
  __syncthreads();

  // Phase C: GEMM2 + bias -> h2 (f32) + column stats
  {
    floatx4 acc2[4] = {};
    for (int kc = 0; kc < 8; ++kc) {
      const int kb = kc * 32 + q * 8;
      const bf16x8 a = *(const bf16x8*)&Hstrip[l15][kb];
#pragma unroll
      for (int nt = 0; nt < 4; ++nt) {
        const bf16x8 b = *(const bf16x8*)(W2 + (size_t)(w * 64 + nt * 16 + l15) * 256 + kb);
        acc2[nt] = __builtin_amdgcn_mfma_f32_16x16x32_bf16(a, b, acc2[nt], 0, 0, 0);
      }
    }
#pragma unroll
    for (int nt = 0; nt < 4; ++nt) {
      const int n = w * 64 + nt * 16 + l15;
      const float bv = b2[n];
      float s = 0.f, s2 = 0.f;
#pragma unroll
      for (int r2 = 0; r2 < 4; ++r2) {
        const int m = q * 4 + r2;
        const float v = acc2[nt][r2] + bv;
        h2[(size_t)(m0 + m) * 256 + n] = v;
        s += v; s2 += v * v;
      }
      s += __shfl_xor(s, 16); s += __shfl_xor(s, 32);
      s2 += __shfl_xor(s2, 16); s2 += __shfl_xor(s2, 32);
      if (q == 0) {
        atomicAdd(&stats[n], s);
        atomicAdd(&stats[256 + n], s2);
      }
    }
  }
}

// ---------------- Y: BN + relu + feat + hb(hi/lo) + next-layer att-e (fused) ----------------
__global__ __launch_bounds__(256) void layer_y(const float* __restrict__ h2,
                                               const float* __restrict__ stats,
                                               const float* __restrict__ gamma,
                                               const float* __restrict__ beta,
                                               const float* __restrict__ maskl,
                                               const __hip_bfloat16* __restrict__ aHi,
                                               const __hip_bfloat16* __restrict__ aLo,
                                               const float* __restrict__ ab1,
                                               const float* __restrict__ aw2,
                                               const float* __restrict__ ab2,
                                               __hip_bfloat16* __restrict__ hbHi,
                                               __hip_bfloat16* __restrict__ hbLo,
                                               __hip_bfloat16* __restrict__ feat,
                                               float* __restrict__ evec, int l) {
  __shared__ __hip_bfloat16 HiS[16][264];
  __shared__ __hip_bfloat16 LoS[16][264];
  __shared__ float red[16][65];
  const int tid = threadIdx.x, w = tid >> 6, lane = tid & 63;
  const int q = lane >> 4, l15 = lane & 15;
  const int m0 = blockIdx.x * 16;
  const float inv_n = 1.f / 8192.f;

  // Phase 1: BN apply. thread -> row i = w*4+q, cols l15*16..+15
  {
    const int i = w * 4 + q;
    const int node = m0 + i;
    const float fm = maskl[node];
#pragma unroll
    for (int cc = 0; cc < 4; ++cc) {
      const int c = l15 * 16 + cc * 4;
      const float4 sA = *(const float4*)&stats[c];
      const float4 sB = *(const float4*)&stats[256 + c];
      const float4 g4 = *(const float4*)&gamma[c];
      const float4 b4 = *(const float4*)&beta[c];
      const float4 v = *(const float4*)&h2[(size_t)node * 256 + c];
      float o[4];
      {
        float mn = sA.x * inv_n; o[0] = fmaxf((v.x - mn) * rsqrtf(sB.x * inv_n - mn * mn + 1e-5f) * g4.x + b4.x, 0.f);
        mn = sA.y * inv_n; o[1] = fmaxf((v.y - mn) * rsqrtf(sB.y * inv_n - mn * mn + 1e-5f) * g4.y + b4.y, 0.f);
        mn = sA.z * inv_n; o[2] = fmaxf((v.z - mn) * rsqrtf(sB.z * inv_n - mn * mn + 1e-5f) * g4.z + b4.z, 0.f);
        mn = sA.w * inv_n; o[3] = fmaxf((v.w - mn) * rsqrtf(sB.w * inv_n - mn * mn + 1e-5f) * g4.w + b4.w, 0.f);
      }
      union { __hip_bfloat16 h[4]; short4 s4; } ph, pl, pf;
#pragma unroll
      for (int k = 0; k < 4; ++k) {
        ph.h[k] = __float2bfloat16(o[k]);
        pl.h[k] = __float2bfloat16(o[k] - __bfloat162float(ph.h[k]));
        pf.h[k] = __float2bfloat16(o[k] * fm);
      }
      *(short4*)(hbHi + (size_t)node * 256 + c) = ph.s4;
      *(short4*)(hbLo + (size_t)node * 256 + c) = pl.s4;
      *(short4*)&HiS[i][c] = ph.s4;
      *(short4*)&LoS[i][c] = pl.s4;
      *(short4*)(feat + (size_t)node * 768 + l * 256 + c) = pf.s4;
    }
  }
  __syncthreads();

  // Phase 2: att-e MLP for next layer (hi/lo split, 3 passes)
  const int n = w * 16 + l15;
  floatx4 acc = {0.f, 0.f, 0.f, 0.f};
#pragma unroll
  for (int pass = 0; pass < 3; ++pass) {
    const __hip_bfloat16(*S)[264] = (pass == 2) ? LoS : HiS;
    const __hip_bfloat16* Wb = (pass == 1) ? aLo : aHi;
    for (int kc = 0; kc < 8; ++kc) {
      const int kb = kc * 32 + q * 8;
      const bf16x8 a = *(const bf16x8*)&S[l15][kb];
      const bf16x8 b = *(const bf16x8*)(Wb + (size_t)n * 256 + kb);
      acc = __builtin_amdgcn_mfma_f32_16x16x32_bf16(a, b, acc, 0, 0, 0);
    }
  }
  const float b1v = ab1[n], w2v = aw2[n];
#pragma unroll
  for (int r2 = 0; r2 < 4; ++r2)
    red[q * 4 + r2][n] = fmaxf(acc[r2] + b1v, 0.f) * w2v;
  __syncthreads();
  if (tid < 16) {
    float s = 0.f;
#pragma unroll
    for (int nn = 0; nn < 64; ++nn) s += red[tid][nn];
    evec[m0 + tid] = s + ab2[0];
  }
}

// ---------------- Y3: BN + feat-l2 (LDS only) + pred GEMM fused ----------------
__global__ __launch_bounds__(256) void layer_y3(const float* __restrict__ h2,
                                                const float* __restrict__ stats,
                                                const float* __restrict__ gamma,
                                                const float* __restrict__ beta,
                                                const float* __restrict__ maskl,
                                                const __hip_bfloat16* __restrict__ feat,
                                                const __hip_bfloat16* __restrict__ predWt,
                                                const float* __restrict__ pred_b,
                                                float* __restrict__ out) {
  __shared__ __hip_bfloat16 F[16][776];
  const int tid = threadIdx.x, w = tid >> 6, lane = tid & 63;
  const int q = lane >> 4, l15 = lane & 15;
  const int m0 = blockIdx.x * 16;
  const float inv_n = 1.f / 8192.f;

  // load feat l0/l1 rows into strip cols 0..511
#pragma unroll
  for (int t = 0; t < 4; ++t) {
    const int idx = t * 256 + tid;
    const int row = idx >> 6, ch = idx & 63;
    const uint4 u = *(const uint4*)(feat + (size_t)(m0 + row) * 768 + ch * 8);
    *(uint4*)&F[row][ch * 8] = u;
  }
  // BN for l2 -> strip cols 512..767
  {
    const int i = w * 4 + q;
    const int node = m0 + i;
    const float fm = maskl[node];
#pragma unroll
    for (int cc = 0; cc < 4; ++cc) {
      const int c = l15 * 16 + cc * 4;
      const float4 sA = *(const float4*)&stats[c];
      const float4 sB = *(const float4*)&stats[256 + c];
      const float4 g4 = *(const float4*)&gamma[c];
      const float4 b4 = *(const float4*)&beta[c];
      const float4 v = *(const float4*)&h2[(size_t)node * 256 + c];
      float o[4];
      {
        float mn = sA.x * inv_n; o[0] = fmaxf((v.x - mn) * rsqrtf(sB.x * inv_n - mn * mn + 1e-5f) * g4.x + b4.x, 0.f);
        mn = sA.y * inv_n; o[1] = fmaxf((v.y - mn) * rsqrtf(sB.y * inv_n - mn * mn + 1e-5f) * g4.y + b4.y, 0.f);
        mn = sA.z * inv_n; o[2] = fmaxf((v.z - mn) * rsqrtf(sB.z * inv_n - mn * mn + 1e-5f) * g4.z + b4.z, 0.f);
        mn = sA.w * inv_n; o[3] = fmaxf((v.w - mn) * rsqrtf(sB.w * inv_n - mn * mn + 1e-5f) * g4.w + b4.w, 0.f);
      }
      union { __hip_bfloat16 h[4]; short4 s4; } pf;
#pragma unroll
      for (int k = 0; k < 4; ++k) pf.h[k] = __float2bfloat16(o[k] * fm);
      *(short4*)&F[i][512 + c] = pf.s4;
    }
  }
  __syncthreads();

  // pred GEMM: out[16,64] = F[16,768] @ predWt[64,768]^T + b
  const int n = w * 16 + l15;
  floatx4 acc = {0.f, 0.f, 0.f, 0.f};
  for (int kc = 0; kc < 24; ++kc) {
    const int kb = kc * 32 + q * 8;
    const bf16x8 a = *(const bf16x8*)&F[l15][kb];
    const bf16x8 b = *(const bf16x8*)(predWt + (size_t)n * 768 + kb);
    acc = __builtin_amdgcn_mfma_f32_16x16x32_bf16(a, b, acc, 0, 0, 0);
  }
  const float bv = pred_b[n];
#pragma unroll
  for (int r2 = 0; r2 < 4; ++r2)
    out[(size_t)(m0 + q * 4 + r2) * 64 + n] = acc[r2] + bv;
}

extern "C" void kernel_launch(void* const* d_in, const int* in_sizes, int n_in,
                              void* d_out, int out_size, void* d_ws, size_t ws_size,
                              hipStream_t stream) {
  (void)in_sizes; (void)n_in; (void)out_size; (void)ws_size;
  const float* graph   = (const float*)d_in[0];
  const float* x       = (const float*)d_in[1];
  const float* att_W1  = (const float*)d_in[2];
  const float* att_b1  = (const float*)d_in[3];
  const float* att_W2  = (const float*)d_in[4];
  const float* att_b2  = (const float*)d_in[5];
  const float* mlp_W1  = (const float*)d_in[6];
  const float* mlp_b1  = (const float*)d_in[7];
  const float* mlp_W2  = (const float*)d_in[8];
  const float* mlp_b2  = (const float*)d_in[9];
  const float* bn_g    = (const float*)d_in[10];
  const float* bn_b    = (const float*)d_in[11];
  const float* mask_W1 = (const float*)d_in[12];
  const float* mask_b1 = (const float*)d_in[13];
  const float* mask_W2 = (const float*)d_in[14];
  const float* mask_b2 = (const float*)d_in[15];
  const float* pred_W  = (const float*)d_in[16];
  const float* pred_b  = (const float*)d_in[17];
  float* out = (float*)d_out;

  char* ws = (char*)d_ws;
  size_t off = 0;
  auto carve = [&](size_t bytes) -> char* {
    char* p = ws + off;
    off += (bytes + 255) & ~(size_t)255;
    return p;
  };
  __hip_bfloat16* Wt1    = (__hip_bfloat16*)carve((size_t)3 * 65536 * 2);
  __hip_bfloat16* Wt2    = (__hip_bfloat16*)carve((size_t)3 * 65536 * 2);
  __hip_bfloat16* attHi  = (__hip_bfloat16*)carve((size_t)3 * 16384 * 2);
  __hip_bfloat16* attLo  = (__hip_bfloat16*)carve((size_t)3 * 16384 * 2);
  __hip_bfloat16* maskHi = (__hip_bfloat16*)carve((size_t)64 * 256 * 2);
  __hip_bfloat16* maskLo = (__hip_bfloat16*)carve((size_t)64 * 256 * 2);
  __hip_bfloat16* predWt = (__hip_bfloat16*)carve((size_t)64 * 768 * 2);
  int*   col_idx = (int*)carve((size_t)N_NODES * MAXD * 4);
  int*   deg     = (int*)carve((size_t)N_NODES * 4);
  float* evec    = (float*)carve((size_t)N_NODES * 4);
  float* maskL   = (float*)carve((size_t)3 * N_NODES * 4);
  float* stats   = (float*)carve((size_t)3 * 512 * 4);
  float* h2      = (float*)carve((size_t)N_NODES * 256 * 4);
  __hip_bfloat16* hbHi = (__hip_bfloat16*)carve((size_t)N_NODES * 256 * 2);
  __hip_bfloat16* hbLo = (__hip_bfloat16*)carve((size_t)N_NODES * 256 * 2);
  __hip_bfloat16* feat = (__hip_bfloat16*)carve((size_t)N_NODES * 768 * 2);

  prep_csr<<<9186, 256, 0, stream>>>(mlp_W1, mlp_W2, att_W1, pred_W, mask_W1, x, graph,
                                     Wt1, Wt2, attHi, attLo, predWt, maskHi, maskLo,
                                     hbHi, hbLo, stats, col_idx, deg);
  emlp_kernel<<<256, 256, 0, stream>>>(hbHi, hbLo, attHi, attLo, att_b1, att_W2, att_b2,
                                       maskHi, maskLo, mask_b1, mask_W2, mask_b2,
                                       evec, maskL);
  for (int l = 0; l < 3; ++l) {
    layer_x<<<512, 256, 0, stream>>>(hbHi, evec, col_idx, deg,
                                     Wt1 + (size_t)l * 65536, mlp_b1 + l * 256,
                                     Wt2 + (size_t)l * 65536, mlp_b2 + l * 256,
                                     h2, stats + l * 512);
    if (l < 2) {
      layer_y<<<512, 256, 0, stream>>>(h2, stats + l * 512, bn_g + l * 256, bn_b + l * 256,
                                       maskL + l * N_NODES,
                                       attHi + (size_t)(l + 1) * 16384,
                                       attLo + (size_t)(l + 1) * 16384,
                                       att_b1 + (l + 1) * 64, att_W2 + (l + 1) * 64,
                                       att_b2 + (l + 1),
                                       hbHi, hbLo, feat, evec, l);
    } else {
      layer_y3<<<512, 256, 0, stream>>>(h2, stats + l * 512, bn_g + l * 256, bn_b + l * 256,
                                        maskL + l * N_NODES, feat, predWt, pred_b, out);
    }
  }
}

// Round 6
// 500.202 us; speedup vs baseline: 1.1577x; 1.1577x over previous
//
#include <hip/hip_runtime.h>
#include <hip/hip_bf16.h>

#define N_NODES 8192
#define MAXD 128

typedef __attribute__((ext_vector_type(8))) __bf16 bf16x8;
typedef __attribute__((ext_vector_type(4))) float floatx4;
typedef float __attribute__((ext_vector_type(4))) f32x4;

__device__ __forceinline__ void async16(void* lds, const void* g) {
  __builtin_amdgcn_global_load_lds((const __attribute__((address_space(1))) void*)g,
                                   (__attribute__((address_space(3))) void*)lds, 16, 0, 0);
}

__device__ __forceinline__ float bfu(unsigned short u) {
  union { unsigned int i; float f; } c; c.i = (unsigned int)u << 16; return c.f;
}

// ---------------- prep (transposes, hi/lo splits, x->bf16, stats zero) + CSR build ----------------
__global__ __launch_bounds__(256) void prep_csr(const float* __restrict__ mlp_W1,
                                                const float* __restrict__ mlp_W2,
                                                const float* __restrict__ att_W1,
                                                const float* __restrict__ pred_W,
                                                const float* __restrict__ mask_W1,
                                                const float* __restrict__ x,
                                                const float* __restrict__ graph,
                                                __hip_bfloat16* __restrict__ Wt1,
                                                __hip_bfloat16* __restrict__ Wt2,
                                                __hip_bfloat16* __restrict__ attHi,
                                                __hip_bfloat16* __restrict__ attLo,
                                                __hip_bfloat16* __restrict__ predWt,
                                                __hip_bfloat16* __restrict__ maskHi,
                                                __hip_bfloat16* __restrict__ maskLo,
                                                __hip_bfloat16* __restrict__ hbHi,
                                                __hip_bfloat16* __restrict__ hbLo,
                                                float* __restrict__ stats,
                                                int* __restrict__ col_idx,
                                                int* __restrict__ deg) {
  __shared__ union { float tile[32][33]; int cnt; } sm;
  const int blk = blockIdx.x, tid = threadIdx.x;
  if (blk >= 994) {  // CSR: block per row, 2048 loads in flight, nontemporal stream
    const int i = blk - 994;
    if (tid == 0) sm.cnt = 0;
    __syncthreads();
    const f32x4* row = (const f32x4*)(graph + (size_t)i * N_NODES);
#pragma unroll
    for (int it = 0; it < 8; ++it) {
      const int idx = it * 256 + tid;
      f32x4 v = __builtin_nontemporal_load(&row[idx]);
      if (v.x > 0.f) { int p = atomicAdd(&sm.cnt, 1); if (p < MAXD) col_idx[(size_t)i * MAXD + p] = idx * 4 + 0; }
      if (v.y > 0.f) { int p = atomicAdd(&sm.cnt, 1); if (p < MAXD) col_idx[(size_t)i * MAXD + p] = idx * 4 + 1; }
      if (v.z > 0.f) { int p = atomicAdd(&sm.cnt, 1); if (p < MAXD) col_idx[(size_t)i * MAXD + p] = idx * 4 + 2; }
      if (v.w > 0.f) { int p = atomicAdd(&sm.cnt, 1); if (p < MAXD) col_idx[(size_t)i * MAXD + p] = idx * 4 + 3; }
    }
    __syncthreads();
    if (tid == 0) deg[i] = sm.cnt < MAXD ? sm.cnt : MAXD;
    return;
  }
  if (blk < 480) {
    const int tx = tid & 31, ty = tid >> 5;
    const float* in; __hip_bfloat16* oh; __hip_bfloat16* ol = nullptr;
    int K, N, kt, nt;
    if (blk < 384) {
      const int z = blk / 64, rem = blk % 64; kt = rem / 8; nt = rem % 8; K = 256; N = 256;
      in = z < 3 ? mlp_W1 + (size_t)z * 65536 : mlp_W2 + (size_t)(z - 3) * 65536;
      oh = z < 3 ? Wt1 + (size_t)z * 65536 : Wt2 + (size_t)(z - 3) * 65536;
    } else if (blk < 432) {
      const int i = blk - 384, z = i / 16, rem = i % 16; kt = rem / 2; nt = rem & 1;
      K = 256; N = 64;
      in = att_W1 + (size_t)z * 16384; oh = attHi + (size_t)z * 16384;
      ol = attLo + (size_t)z * 16384;
    } else {
      const int i = blk - 432; kt = i / 2; nt = i & 1; K = 768; N = 64;
      in = pred_W; oh = predWt;
    }
    const int k0 = kt * 32, n0 = nt * 32;
#pragma unroll
    for (int r = 0; r < 4; ++r)
      sm.tile[ty + r * 8][tx] = in[(size_t)(k0 + ty + r * 8) * N + n0 + tx];
    __syncthreads();
#pragma unroll
    for (int r = 0; r < 4; ++r) {
      const float v = sm.tile[tx][ty + r * 8];
      const __hip_bfloat16 hi = __float2bfloat16(v);
      oh[(size_t)(n0 + ty + r * 8) * K + k0 + tx] = hi;
      if (ol)
        ol[(size_t)(n0 + ty + r * 8) * K + k0 + tx] =
            __float2bfloat16(v - __bfloat162float(hi));
    }
  } else if (blk == 480) {
    for (int i = tid; i < 16384; i += 256) {
      const int n = i >> 8, k = i & 255;
      const float v = (n < 54) ? mask_W1[k * 54 + n] : 0.f;
      const __hip_bfloat16 hi = __float2bfloat16(v);
      maskHi[n * 256 + k] = hi;
      maskLo[n * 256 + k] = __float2bfloat16(v - __bfloat162float(hi));
    }
  } else if (blk == 481) {
    for (int i = tid; i < 1536; i += 256) stats[i] = 0.f;
  } else {
    const float4* xv = (const float4*)x;
    const int base = (blk - 482) * 1024;
#pragma unroll
    for (int it = 0; it < 4; ++it) {
      const int i = base + it * 256 + tid;
      const float4 v = xv[i];
      union { __hip_bfloat16 h[4]; short4 s4; } ph, pl;
      ph.h[0] = __float2bfloat16(v.x); ph.h[1] = __float2bfloat16(v.y);
      ph.h[2] = __float2bfloat16(v.z); ph.h[3] = __float2bfloat16(v.w);
      pl.h[0] = __float2bfloat16(v.x - __bfloat162float(ph.h[0]));
      pl.h[1] = __float2bfloat16(v.y - __bfloat162float(ph.h[1]));
      pl.h[2] = __float2bfloat16(v.z - __bfloat162float(ph.h[2]));
      pl.h[3] = __float2bfloat16(v.w - __bfloat162float(ph.h[3]));
      ((short4*)hbHi)[i] = ph.s4;
      ((short4*)hbLo)[i] = pl.s4;
    }
  }
}

// ---------------- e/mask MLP v2: stage A once in LDS, W direct from L2, no inner barriers ----------------
__global__ __launch_bounds__(256) void emlp2_kernel(
    const __hip_bfloat16* __restrict__ hbHi, const __hip_bfloat16* __restrict__ hbLo,
    const __hip_bfloat16* __restrict__ aHi, const __hip_bfloat16* __restrict__ aLo,
    const float* __restrict__ ab1, const float* __restrict__ aw2, const float* __restrict__ ab2,
    const __hip_bfloat16* __restrict__ mHi, const __hip_bfloat16* __restrict__ mLo,
    const float* __restrict__ mb1, const float* __restrict__ mw2, const float* __restrict__ mb2,
    float* __restrict__ evec, float* __restrict__ maskL) {
  __shared__ union {
    struct { __hip_bfloat16 Hi[64][264]; __hip_bfloat16 Lo[64][264]; } s;
    float red[64][65];
  } sm;
  const int tid = threadIdx.x, w = tid >> 6, lane = tid & 63;
  const int q = lane >> 4, l15 = lane & 15;
  const bool is_mask = blockIdx.x >= 128;
  const int m0 = (is_mask ? (int)blockIdx.x - 128 : (int)blockIdx.x) * 64;
#pragma unroll
  for (int t = 0; t < 8; ++t) {  // stage 64 rows hi+lo (once)
    const int idx = t * 256 + tid;
    const int row = idx >> 5, ch = idx & 31;
    *(uint4*)&sm.s.Hi[row][ch * 8] = *(const uint4*)(hbHi + (size_t)(m0 + row) * 256 + ch * 8);
    *(uint4*)&sm.s.Lo[row][ch * 8] = *(const uint4*)(hbLo + (size_t)(m0 + row) * 256 + ch * 8);
  }
  __syncthreads();
  const __hip_bfloat16* Whi = is_mask ? mHi : aHi;
  const __hip_bfloat16* Wlo = is_mask ? mLo : aLo;
  const int n = w * 16 + l15;
  floatx4 acc[4] = {};
  for (int kc = 0; kc < 8; ++kc) {
    const int kb = kc * 32 + q * 8;
    const bf16x8 bHi = *(const bf16x8*)(Whi + (size_t)n * 256 + kb);
    const bf16x8 bLo = *(const bf16x8*)(Wlo + (size_t)n * 256 + kb);
#pragma unroll
    for (int mt = 0; mt < 4; ++mt) {
      const bf16x8 ah = *(const bf16x8*)&sm.s.Hi[mt * 16 + l15][kb];
      const bf16x8 al = *(const bf16x8*)&sm.s.Lo[mt * 16 + l15][kb];
      acc[mt] = __builtin_amdgcn_mfma_f32_16x16x32_bf16(ah, bHi, acc[mt], 0, 0, 0);
      acc[mt] = __builtin_amdgcn_mfma_f32_16x16x32_bf16(ah, bLo, acc[mt], 0, 0, 0);
      acc[mt] = __builtin_amdgcn_mfma_f32_16x16x32_bf16(al, bHi, acc[mt], 0, 0, 0);
    }
  }
  float b1v, w2v, b2v;
  if (is_mask) {
    b1v = n < 54 ? mb1[n] : 0.f;
    w2v = n < 54 ? mw2[n] : 0.f;
    b2v = mb2[0];
  } else {
    b1v = ab1[n]; w2v = aw2[n]; b2v = ab2[0];
  }
  __syncthreads();  // strips -> red (union reuse)
#pragma unroll
  for (int mt = 0; mt < 4; ++mt)
#pragma unroll
    for (int r2 = 0; r2 < 4; ++r2)
      sm.red[n][mt * 16 + q * 4 + r2] = fmaxf(acc[mt][r2] + b1v, 0.f) * w2v;
  __syncthreads();
  if (tid < 64) {
    float s = 0.f;
#pragma unroll
    for (int nn = 0; nn < 64; ++nn) s += sm.red[nn][tid];
    const float z = s + b2v;
    if (!is_mask) {
      evec[m0 + tid] = z;
    } else {
      const float thr = 3.f / (1.f + expf(-z));
#pragma unroll
      for (int li = 0; li < 3; ++li) {
        const float dd = (float)li - thr;
        maskL[li * N_NODES + m0 + tid] = expf(-dd * dd);
      }
    }
  }
}

// ---------------- sparse softmax aggregation: wave per node, bf16 gather ----------------
__global__ __launch_bounds__(256) void agg4(const __hip_bfloat16* __restrict__ hb,
                                            const float* __restrict__ e,
                                            const int* __restrict__ col_idx,
                                            const int* __restrict__ deg,
                                            __hip_bfloat16* __restrict__ hagg) {
  __shared__ int cols[4][MAXD];
  __shared__ float wts[4][MAXD];
  const int w = threadIdx.x >> 6, lane = threadIdx.x & 63;
  const int node = blockIdx.x * 4 + w;
  const int d = deg[node];
  int c0 = 0, c1 = 0;
  float e0 = -3.0e38f, e1 = -3.0e38f;
  if (lane < d) { c0 = col_idx[(size_t)node * MAXD + lane]; e0 = e[c0]; }
  if (lane + 64 < d) { c1 = col_idx[(size_t)node * MAXD + lane + 64]; e1 = e[c1]; }
  float mx = fmaxf(e0, e1);
#pragma unroll
  for (int off = 32; off; off >>= 1) mx = fmaxf(mx, __shfl_xor(mx, off));
  const float p0 = lane < d ? expf(e0 - mx) : 0.f;
  const float p1 = lane + 64 < d ? expf(e1 - mx) : 0.f;
  float s = p0 + p1;
#pragma unroll
  for (int off = 32; off; off >>= 1) s += __shfl_xor(s, off);
  const float scale = (float)d / s;
  cols[w][lane] = c0; wts[w][lane] = p0 * scale;
  cols[w][lane + 64] = c1; wts[w][lane + 64] = p1 * scale;
  __syncthreads();
  float4 a = {0.f, 0.f, 0.f, 0.f};
  int j = 0;
  for (; j + 2 <= d; j += 2) {
    const int cc0 = cols[w][j], cc1 = cols[w][j + 1];
    const float w0 = wts[w][j], w1 = wts[w][j + 1];
    const ushort4 u0 = *(const ushort4*)(hb + (size_t)cc0 * 256 + lane * 4);
    const ushort4 u1 = *(const ushort4*)(hb + (size_t)cc1 * 256 + lane * 4);
    a.x += w0 * bfu(u0.x) + w1 * bfu(u1.x);
    a.y += w0 * bfu(u0.y) + w1 * bfu(u1.y);
    a.z += w0 * bfu(u0.z) + w1 * bfu(u1.z);
    a.w += w0 * bfu(u0.w) + w1 * bfu(u1.w);
  }
  if (j < d) {
    const int cc0 = cols[w][j];
    const float w0 = wts[w][j];
    const ushort4 u0 = *(const ushort4*)(hb + (size_t)cc0 * 256 + lane * 4);
    a.x += w0 * bfu(u0.x); a.y += w0 * bfu(u0.y);
    a.z += w0 * bfu(u0.z); a.w += w0 * bfu(u0.w);
  }
  union { __hip_bfloat16 h[4]; short4 s4; } pk;
  pk.h[0] = __float2bfloat16(a.x); pk.h[1] = __float2bfloat16(a.y);
  pk.h[2] = __float2bfloat16(a.z); pk.h[3] = __float2bfloat16(a.w);
  *(short4*)(hagg + (size_t)node * 256 + lane * 4) = pk.s4;
}

// ---------------- 64x64 MFMA tile accumulate (proven) ----------------
__device__ __forceinline__ void gemm_acc(char* AsB, char* WsB,
                                         const __hip_bfloat16* __restrict__ A,
                                         const __hip_bfloat16* __restrict__ Bt,
                                         int K, int m0, int n0, floatx4* acc) {
  const int tid = threadIdx.x, w = tid >> 6, lane = tid & 63;
  const int q = lane >> 4, l15 = lane & 15;
  const int nKT = K >> 6;
  for (int kt = 0; kt < nKT; ++kt) {
    const int kbase = kt * 64;
#pragma unroll
    for (int r = 0; r < 2; ++r) {
      const int s = w * 128 + r * 64 + lane;
      const int m = s >> 3;
      const int gch = (s & 7) ^ (m & 7);
      async16(AsB + (size_t)(w * 128 + r * 64) * 16,
              (const void*)(A + (size_t)(m0 + m) * K + kbase + gch * 8));
      async16(WsB + (size_t)(w * 128 + r * 64) * 16,
              (const void*)(Bt + (size_t)(n0 + m) * K + kbase + gch * 8));
    }
    __syncthreads();
#pragma unroll
    for (int kk = 0; kk < 2; ++kk) {
      const int gq = kk * 4 + q;
      const int nsl = w * 16 + l15;
      bf16x8 b = *(const bf16x8*)(WsB + (size_t)(nsl * 8 + (gq ^ (nsl & 7))) * 16);
#pragma unroll
      for (int mt = 0; mt < 4; ++mt) {
        const int msl = mt * 16 + l15;
        bf16x8 a = *(const bf16x8*)(AsB + (size_t)(msl * 8 + (gq ^ (msl & 7))) * 16);
        acc[mt] = __builtin_amdgcn_mfma_f32_16x16x32_bf16(a, b, acc[mt], 0, 0, 0);
      }
    }
    __syncthreads();
  }
}

// ---------------- bf16 MFMA GEMM: C = A @ Wt^T + bias; optional stats ----------------
template <bool OUT_BF16, bool RELU, bool STATS>
__global__ __launch_bounds__(256) void gemm_bf16(const __hip_bfloat16* __restrict__ A,
                                                 const __hip_bfloat16* __restrict__ Wt,
                                                 const float* __restrict__ bias,
                                                 void* __restrict__ Cout, int K, int ldc,
                                                 float* __restrict__ stats) {
  __shared__ __align__(16) char As[8192];
  __shared__ __align__(16) char Ws[8192];
  const int tid = threadIdx.x;
  const int w = tid >> 6;
  const int lane = tid & 63;
  const int m0 = blockIdx.x * 64;
  const int n0 = blockIdx.y * 64;
  const int q = lane >> 4, l15 = lane & 15;
  floatx4 acc[4] = {};
  gemm_acc(As, Ws, A, Wt, K, m0, n0, acc);
  const int n = n0 + w * 16 + l15;
  const float bv = bias[n];
  float s = 0.f, s2 = 0.f;
#pragma unroll
  for (int mt = 0; mt < 4; ++mt) {
#pragma unroll
    for (int r2 = 0; r2 < 4; ++r2) {
      const int m = m0 + mt * 16 + q * 4 + r2;
      float v = acc[mt][r2] + bv;
      if (RELU) v = fmaxf(v, 0.f);
      if (STATS) { s += v; s2 += v * v; }
      if (OUT_BF16)
        ((__hip_bfloat16*)Cout)[(size_t)m * ldc + n] = __float2bfloat16(v);
      else
        ((float*)Cout)[(size_t)m * ldc + n] = v;
    }
  }
  if (STATS) {
    s += __shfl_xor(s, 16); s += __shfl_xor(s, 32);
    s2 += __shfl_xor(s2, 16); s2 += __shfl_xor(s2, 32);
    if (q == 0) {
      atomicAdd(&stats[n], s);
      atomicAdd(&stats[256 + n], s2);
    }
  }
}

// ---------------- BN apply + ReLU -> hb hi/lo (bf16) + masked feat (bf16) ----------------
__global__ __launch_bounds__(256) void bn_kernel(const float* __restrict__ h2,
                                                 const float* __restrict__ stats,
                                                 const float* __restrict__ gamma,
                                                 const float* __restrict__ beta,
                                                 const float* __restrict__ maskl,
                                                 __hip_bfloat16* __restrict__ hbHi,
                                                 __hip_bfloat16* __restrict__ hbLo,
                                                 __hip_bfloat16* __restrict__ feat,
                                                 int l) {
  const int w = threadIdx.x >> 6, lane = threadIdx.x & 63;
  const int node = blockIdx.x * 4 + w;
  const int c0 = lane * 4;
  const float inv_n = 1.f / 8192.f;
  const float4 sA = *(const float4*)&stats[c0];
  const float4 sB = *(const float4*)&stats[256 + c0];
  const float4 g4 = *(const float4*)&gamma[c0];
  const float4 b4 = *(const float4*)&beta[c0];
  float mean[4] = {sA.x * inv_n, sA.y * inv_n, sA.z * inv_n, sA.w * inv_n};
  float istd[4];
  istd[0] = rsqrtf(sB.x * inv_n - mean[0] * mean[0] + 1e-5f) * g4.x;
  istd[1] = rsqrtf(sB.y * inv_n - mean[1] * mean[1] + 1e-5f) * g4.y;
  istd[2] = rsqrtf(sB.z * inv_n - mean[2] * mean[2] + 1e-5f) * g4.z;
  istd[3] = rsqrtf(sB.w * inv_n - mean[3] * mean[3] + 1e-5f) * g4.w;
  const float bb[4] = {b4.x, b4.y, b4.z, b4.w};
  const float4 v = *(const float4*)&h2[(size_t)node * 256 + c0];
  float o[4];
  o[0] = fmaxf((v.x - mean[0]) * istd[0] + bb[0], 0.f);
  o[1] = fmaxf((v.y - mean[1]) * istd[1] + bb[1], 0.f);
  o[2] = fmaxf((v.z - mean[2]) * istd[2] + bb[2], 0.f);
  o[3] = fmaxf((v.w - mean[3]) * istd[3] + bb[3], 0.f);
  union { __hip_bfloat16 h[4]; short4 s4; } ph, pl, pf;
#pragma unroll
  for (int i = 0; i < 4; ++i) {
    ph.h[i] = __float2bfloat16(o[i]);
    pl.h[i] = __float2bfloat16(o[i] - __bfloat162float(ph.h[i]));
  }
  *(short4*)(hbHi + (size_t)node * 256 + c0) = ph.s4;
  *(short4*)(hbLo + (size_t)node * 256 + c0) = pl.s4;
  const float fm = maskl[node];
#pragma unroll
  for (int i = 0; i < 4; ++i) pf.h[i] = __float2bfloat16(o[i] * fm);
  *(short4*)(feat + (size_t)node * 768 + l * 256 + c0) = pf.s4;
}

// ---------------- Y3: BN(l2) + feat-l2 in LDS + pred GEMM fused ----------------
__global__ __launch_bounds__(256) void layer_y3(const float* __restrict__ h2,
                                                const float* __restrict__ stats,
                                                const float* __restrict__ gamma,
                                                const float* __restrict__ beta,
                                                const float* __restrict__ maskl,
                                                const __hip_bfloat16* __restrict__ feat,
                                                const __hip_bfloat16* __restrict__ predWt,
                                                const float* __restrict__ pred_b,
                                                float* __restrict__ out) {
  __shared__ __hip_bfloat16 F[16][776];
  const int tid = threadIdx.x, w = tid >> 6, lane = tid & 63;
  const int q = lane >> 4, l15 = lane & 15;
  const int m0 = blockIdx.x * 16;
  const float inv_n = 1.f / 8192.f;
#pragma unroll
  for (int t = 0; t < 4; ++t) {  // feat l0/l1 -> cols 0..511
    const int idx = t * 256 + tid;
    const int row = idx >> 6, ch = idx & 63;
    const uint4 u = *(const uint4*)(feat + (size_t)(m0 + row) * 768 + ch * 8);
    *(uint4*)&F[row][ch * 8] = u;
  }
  {  // BN l2 -> cols 512..767
    const int i = w * 4 + q;
    const int node = m0 + i;
    const float fm = maskl[node];
#pragma unroll
    for (int cc = 0; cc < 4; ++cc) {
      const int c = l15 * 16 + cc * 4;
      const float4 sA = *(const float4*)&stats[c];
      const float4 sB = *(const float4*)&stats[256 + c];
      const float4 g4 = *(const float4*)&gamma[c];
      const float4 b4 = *(const float4*)&beta[c];
      const float4 v = *(const float4*)&h2[(size_t)node * 256 + c];
      float o[4];
      {
        float mn = sA.x * inv_n; o[0] = fmaxf((v.x - mn) * rsqrtf(sB.x * inv_n - mn * mn + 1e-5f) * g4.x + b4.x, 0.f);
        mn = sA.y * inv_n; o[1] = fmaxf((v.y - mn) * rsqrtf(sB.y * inv_n - mn * mn + 1e-5f) * g4.y + b4.y, 0.f);
        mn = sA.z * inv_n; o[2] = fmaxf((v.z - mn) * rsqrtf(sB.z * inv_n - mn * mn + 1e-5f) * g4.z + b4.z, 0.f);
        mn = sA.w * inv_n; o[3] = fmaxf((v.w - mn) * rsqrtf(sB.w * inv_n - mn * mn + 1e-5f) * g4.w + b4.w, 0.f);
      }
      union { __hip_bfloat16 h[4]; short4 s4; } pf;
#pragma unroll
      for (int k = 0; k < 4; ++k) pf.h[k] = __float2bfloat16(o[k] * fm);
      *(short4*)&F[i][512 + c] = pf.s4;
    }
  }
  __syncthreads();
  const int n = w * 16 + l15;
  floatx4 acc = {0.f, 0.f, 0.f, 0.f};
  for (int kc = 0; kc < 24; ++kc) {
    const int kb = kc * 32 + q * 8;
    const bf16x8 a = *(const bf16x8*)&F[l15][kb];
    const bf16x8 b = *(const bf16x8*)(predWt + (size_t)n * 768 + kb);
    acc = __builtin_amdgcn_mfma_f32_16x16x32_bf16(a, b, acc, 0, 0, 0);
  }
  const float bv = pred_b[n];
#pragma unroll
  for (int r2 = 0; r2 < 4; ++r2)
    out[(size_t)(m0 + q * 4 + r2) * 64 + n] = acc[r2] + bv;
}

extern "C" void kernel_launch(void* const* d_in, const int* in_sizes, int n_in,
                              void* d_out, int out_size, void* d_ws, size_t ws_size,
                              hipStream_t stream) {
  (void)in_sizes; (void)n_in; (void)out_size; (void)ws_size;
  const float* graph   = (const float*)d_in[0];
  const float* x       = (const float*)d_in[1];
  const float* att_W1  = (const float*)d_in[2];
  const float* att_b1  = (const float*)d_in[3];
  const float* att_W2  = (const float*)d_in[4];
  const float* att_b2  = (const float*)d_in[5];
  const float* mlp_W1  = (const float*)d_in[6];
  const float* mlp_b1  = (const float*)d_in[7];
  const float* mlp_W2  = (const float*)d_in[8];
  const float* mlp_b2  = (const float*)d_in[9];
  const float* bn_g    = (const float*)d_in[10];
  const float* bn_b    = (const float*)d_in[11];
  const float* mask_W1 = (const float*)d_in[12];
  const float* mask_b1 = (const float*)d_in[13];
  const float* mask_W2 = (const float*)d_in[14];
  const float* mask_b2 = (const float*)d_in[15];
  const float* pred_W  = (const float*)d_in[16];
  const float* pred_b  = (const float*)d_in[17];
  float* out = (float*)d_out;

  char* ws = (char*)d_ws;
  size_t off = 0;
  auto carve = [&](size_t bytes) -> char* {
    char* p = ws + off;
    off += (bytes + 255) & ~(size_t)255;
    return p;
  };
  __hip_bfloat16* Wt1    = (__hip_bfloat16*)carve((size_t)3 * 65536 * 2);
  __hip_bfloat16* Wt2    = (__hip_bfloat16*)carve((size_t)3 * 65536 * 2);
  __hip_bfloat16* attHi  = (__hip_bfloat16*)carve((size_t)3 * 16384 * 2);
  __hip_bfloat16* attLo  = (__hip_bfloat16*)carve((size_t)3 * 16384 * 2);
  __hip_bfloat16* maskHi = (__hip_bfloat16*)carve((size_t)64 * 256 * 2);
  __hip_bfloat16* maskLo = (__hip_bfloat16*)carve((size_t)64 * 256 * 2);
  __hip_bfloat16* predWt = (__hip_bfloat16*)carve((size_t)64 * 768 * 2);
  int*   col_idx = (int*)carve((size_t)N_NODES * MAXD * 4);
  int*   deg     = (int*)carve((size_t)N_NODES * 4);
  float* evec    = (float*)carve((size_t)N_NODES * 4);
  float* maskL   = (float*)carve((size_t)3 * N_NODES * 4);
  float* stats   = (float*)carve((size_t)3 * 512 * 4);
  float* h2      = (float*)carve((size_t)N_NODES * 256 * 4);
  __hip_bfloat16* hbHi = (__hip_bfloat16*)carve((size_t)N_NODES * 256 * 2);
  __hip_bfloat16* hbLo = (__hip_bfloat16*)carve((size_t)N_NODES * 256 * 2);
  __hip_bfloat16* hagg = (__hip_bfloat16*)carve((size_t)N_NODES * 256 * 2);
  __hip_bfloat16* H1   = (__hip_bfloat16*)carve((size_t)N_NODES * 256 * 2);
  __hip_bfloat16* feat = (__hip_bfloat16*)carve((size_t)N_NODES * 768 * 2);

  prep_csr<<<9186, 256, 0, stream>>>(mlp_W1, mlp_W2, att_W1, pred_W, mask_W1, x, graph,
                                     Wt1, Wt2, attHi, attLo, predWt, maskHi, maskLo,
                                     hbHi, hbLo, stats, col_idx, deg);
  emlp2_kernel<<<256, 256, 0, stream>>>(hbHi, hbLo, attHi, attLo, att_b1, att_W2, att_b2,
                                        maskHi, maskLo, mask_b1, mask_W2, mask_b2,
                                        evec, maskL);
  for (int l = 0; l < 3; ++l) {
    agg4<<<N_NODES / 4, 256, 0, stream>>>(hbHi, evec, col_idx, deg, hagg);
    gemm_bf16<true, true, false><<<dim3(128, 4), 256, 0, stream>>>(
        hagg, Wt1 + (size_t)l * 65536, mlp_b1 + l * 256, H1, 256, 256, nullptr);
    gemm_bf16<false, false, true><<<dim3(128, 4), 256, 0, stream>>>(
        H1, Wt2 + (size_t)l * 65536, mlp_b2 + l * 256, h2, 256, 256, stats + l * 512);
    if (l < 2) {
      bn_kernel<<<N_NODES / 4, 256, 0, stream>>>(h2, stats + l * 512, bn_g + l * 256,
                                                 bn_b + l * 256, maskL + l * N_NODES,
                                                 hbHi, hbLo, feat, l);
      emlp2_kernel<<<128, 256, 0, stream>>>(hbHi, hbLo,
                                            attHi + (size_t)(l + 1) * 16384,
                                            attLo + (size_t)(l + 1) * 16384,
                                            att_b1 + (l + 1) * 64, att_W2 + (l + 1) * 64,
                                            att_b2 + (l + 1),
                                            nullptr, nullptr, nullptr, nullptr, nullptr,
                                            evec, maskL);
    } else {
      layer_y3<<<512, 256, 0, stream>>>(h2, stats + l * 512, bn_g + l * 256, bn_b + l * 256,
                                        maskL + l * N_NODES, feat, predWt, pred_b, out);
    }
  }
}